// Round 2
// baseline (11144.363 us; speedup 1.0000x reference)
//
#include <hip/hip_runtime.h>
#include <stdint.h>

// AvatarNet style-swap, MI355X fp32 implementation.
// Pipeline: center -> cov (batched GEMM-NT) -> Newton-Schulz (cov^{+-1/2}, batched)
//        -> whiten apply -> patch-norm -> fused score GEMM + argmax (atomicMax on packed u64)
//        -> one-hot transpose-conv gather -> recolor GEMM + blend epilogue.

#define C_   512
#define H_   64
#define W_   64
#define HW_  4096
#define P_   3844            // (64-2)^2 patches per image
#define PW_  62
#define NIT_ 10              // Newton-Schulz iterations (scalar recursion converges in ~9 from x0=0.056)

static const long CHW_ = (long)C_ * HW_;   // 2,097,152
static const long CC_  = (long)C_ * C_;    // 262,144 = 2^18

enum { GM_COV = 0, GM_NST = 1, GM_PLAIN = 2, GM_SCALE_RCP = 3, GM_NSMUL = 4, GM_NSMUL_F = 5, GM_COLOR = 6 };

// ---------------------------------------------------------------------------
// Generic batched 64x64-tile fp32 GEMM, 256 threads, 4x4 micro-tile.
// MODE selects pointer setup + epilogue. TB: B is [N,K] row-major (B^T used).
// ---------------------------------------------------------------------------
template<int MODE, bool TB>
__global__ __launch_bounds__(256)
void gemm_k(const float* __restrict__ A, const float* __restrict__ Bm, float* __restrict__ Cm_,
            const float* __restrict__ sarr, const float* __restrict__ ex1, const float* __restrict__ ex2,
            int M, int N, int K, long sA, long sB, long sC, long sE1, float cscale)
{
    int z = blockIdx.z;
    const float* Ab; const float* Bb; float* Cb;
    float fs = 1.0f;
    if (MODE == GM_NSMUL || MODE == GM_NSMUL_F) {
        // A param = Y base, Bm param = Z base, ex1 = T base; out slab = [Y2(8) | Z2(8)]
        if (z < 8) {
            Ab = A   + (long)z * CC_;          // Y
            Bb = ex1 + (long)z * CC_;          // T
            if (MODE == GM_NSMUL_F) fs = sqrtf(sarr[z]);        // Y_final *= sqrt(s)
        } else {
            Ab = ex1 + (long)(z - 8) * CC_;    // T
            Bb = Bm  + (long)(z - 8) * CC_;    // Z
            if (MODE == GM_NSMUL_F) fs = rsqrtf(sarr[z - 8]);   // Z_final *= 1/sqrt(s)
        }
        Cb = Cm_ + (long)z * CC_;
    } else {
        Ab = A   + (long)z * sA;
        Bb = Bm  + (long)z * sB;
        Cb = Cm_ + (long)z * sC;
        if (MODE == GM_SCALE_RCP) fs = 1.0f / sarr[z];
    }

    __shared__ float As[16][64];   // [k][i]
    __shared__ float Bs[16][64];   // [k][j]

    int tid = threadIdx.x;
    int tx = tid & 15, ty = tid >> 4;
    int i0 = blockIdx.x * 64;
    int j0 = blockIdx.y * 64;

    int lr = tid >> 2;             // 0..63
    int lk = (tid & 3) << 2;       // 0,4,8,12

    float acc[4][4] = {};

    for (int k0 = 0; k0 < K; k0 += 16) {
        float4 va = *(const float4*)(Ab + (long)(i0 + lr) * K + (k0 + lk));
        As[lk + 0][lr] = va.x; As[lk + 1][lr] = va.y; As[lk + 2][lr] = va.z; As[lk + 3][lr] = va.w;
        if (TB) {
            float4 vb = *(const float4*)(Bb + (long)(j0 + lr) * K + (k0 + lk));
            Bs[lk + 0][lr] = vb.x; Bs[lk + 1][lr] = vb.y; Bs[lk + 2][lr] = vb.z; Bs[lk + 3][lr] = vb.w;
        } else {
            int kr = tid >> 4, jc = (tid & 15) << 2;
            float4 vb = *(const float4*)(Bb + (long)(k0 + kr) * N + (j0 + jc));
            *(float4*)&Bs[kr][jc] = vb;
        }
        __syncthreads();
        #pragma unroll
        for (int k = 0; k < 16; ++k) {
            float4 av = *(const float4*)&As[k][ty * 4];
            float4 bv = *(const float4*)&Bs[k][tx * 4];
            acc[0][0] += av.x * bv.x; acc[0][1] += av.x * bv.y; acc[0][2] += av.x * bv.z; acc[0][3] += av.x * bv.w;
            acc[1][0] += av.y * bv.x; acc[1][1] += av.y * bv.y; acc[1][2] += av.y * bv.z; acc[1][3] += av.y * bv.w;
            acc[2][0] += av.z * bv.x; acc[2][1] += av.z * bv.y; acc[2][2] += av.z * bv.z; acc[2][3] += av.z * bv.w;
            acc[3][0] += av.w * bv.x; acc[3][1] += av.w * bv.y; acc[3][2] += av.w * bv.z; acc[3][3] += av.w * bv.w;
        }
        __syncthreads();
    }

    #pragma unroll
    for (int u = 0; u < 4; ++u) {
        int row  = i0 + ty * 4 + u;
        int col0 = j0 + tx * 4;
        float o[4];
        if (MODE == GM_COLOR) {
            const float* cv = ex1 + (long)z * sE1 + (long)row * N + col0;
            float mu = ex2[z * C_ + row];
            #pragma unroll
            for (int v = 0; v < 4; ++v) o[v] = 0.5f * cv[v] + 0.5f * (acc[u][v] + mu);
        } else {
            #pragma unroll
            for (int v = 0; v < 4; ++v) {
                if (MODE == GM_COV)      o[v] = acc[u][v] * cscale;
                else if (MODE == GM_NST) o[v] = (row == col0 + v ? 1.5f : 0.0f) - 0.5f * acc[u][v];
                else                     o[v] = acc[u][v] * fs;    // PLAIN (fs=1) / SCALE_RCP / NSMUL(_F)
            }
        }
        *(float4*)&Cb[(long)row * N + col0] = make_float4(o[0], o[1], o[2], o[3]);
    }
}

// --------------------------------------------------------------------------- mean + center
__global__ __launch_bounds__(256)
void k_center(const float* __restrict__ content, const float* __restrict__ style,
              float* __restrict__ xc, float* __restrict__ means)
{
    int bz = blockIdx.x;                // 0..4095 : z*512 + c, z: 0-3 content, 4-7 style
    int z = bz >> 9, c = bz & 511;
    const float* src = (z < 4) ? (content + ((long)z * C_ + c) * HW_)
                               : (style   + ((long)(z - 4) * C_ + c) * HW_);
    float* dst = xc + (long)bz * HW_;
    int tid = threadIdx.x;
    float s = 0.f;
    for (int k = tid; k < HW_; k += 256) s += src[k];
    __shared__ float red[4];
    #pragma unroll
    for (int m = 32; m >= 1; m >>= 1) s += __shfl_down(s, m);
    if ((tid & 63) == 0) red[tid >> 6] = s;
    __syncthreads();
    float mean = (red[0] + red[1] + red[2] + red[3]) * (1.0f / HW_);
    for (int k = tid; k < HW_; k += 256) dst[k] = src[k] - mean;
    if (tid == 0) means[bz] = mean;
}

// --------------------------------------------------------------------------- inf-norm of cov (Gershgorin bound on lambda_max)
__global__ void k_infnorm(const float* __restrict__ cov, float* __restrict__ snorm)
{
    int z = blockIdx.x; int tid = threadIdx.x;
    const float* Mz = cov + (long)z * CC_;
    for (int r = tid; r < C_; r += 256) {
        const float4* row = (const float4*)(Mz + (long)r * C_);
        float s = 0.f;
        for (int k = 0; k < C_ / 4; ++k) {
            float4 v = row[k];
            s += fabsf(v.x) + fabsf(v.y) + fabsf(v.z) + fabsf(v.w);
        }
        atomicMax((unsigned*)&snorm[z], __float_as_uint(s));  // positive floats: bit-order == value-order
    }
}

// --------------------------------------------------------------------------- T1 = 1.5I - 0.5*cov/s ; also Z1 = T1 (dual store)
__global__ void k_nsinit(const float* __restrict__ cov, const float* __restrict__ snorm,
                         float* __restrict__ T, float* __restrict__ Z1)
{
    long i = (long)blockIdx.x * 256 + threadIdx.x;     // 8*CC elements
    int z = (int)(i >> 18);                            // CC_ = 2^18
    long rc = i & (CC_ - 1);
    int row = (int)(rc >> 9), col = (int)(rc & 511);
    float v = -0.5f * cov[i] / snorm[z];
    if (row == col) v += 1.5f;
    T[i] = v;
    Z1[i] = v;
}

// --------------------------------------------------------------------------- q[b,y,x] = sum_c nsw^2
__global__ void k_q(const float* __restrict__ nsw, float* __restrict__ q)
{
    int b = blockIdx.x, y = blockIdx.y * 4 + threadIdx.y, x = threadIdx.x;
    const float* base = nsw + (long)b * CHW_ + y * W_ + x;
    float s = 0.f;
    for (int c = 0; c < C_; ++c) { float v = base[(long)c * HW_]; s += v * v; }
    q[(long)b * HW_ + y * W_ + x] = s;
}

// --------------------------------------------------------------------------- rknorm[b,p] = 1/sqrt(sum 3x3 of q)
__global__ void k_rkn(const float* __restrict__ q, float* __restrict__ rkn)
{
    int b = blockIdx.x;
    const float* qb = q + (long)b * HW_;
    for (int p = threadIdx.x; p < P_; p += 256) {
        int pu = p / PW_, pv = p % PW_;
        float s = 0.f;
        #pragma unroll
        for (int i = 0; i < 3; ++i)
            #pragma unroll
            for (int j = 0; j < 3; ++j)
                s += qb[(pu + i) * W_ + pv + j];
        rkn[b * P_ + p] = rsqrtf(fmaxf(s, 1e-20f));
    }
}

// ---------------------------------------------------------------------------
// Fused score GEMM + argmax. Tile: 128 pixels (2 rows) x 128 patches, 256 thr,
// 8x8 micro-tile, K-chunk = 8 channels x 9 taps. Epilogue: scale by 1/knorm,
// shfl-reduce (score,idx) over the 16-lane patch dimension, atomicMax packed u64.
// ---------------------------------------------------------------------------
#define SC_KC 8
__global__ __launch_bounds__(256)
void k_score(const float* __restrict__ nc, const float* __restrict__ nsw,
             const float* __restrict__ rkn, unsigned long long* __restrict__ packed)
{
    int b  = blockIdx.z;
    int p0 = blockIdx.x * 128;
    int y0 = blockIdx.y * 2;
    const float* ncb = nc  + (long)b * CHW_;
    const float* nsb = nsw + (long)b * CHW_;

    __shared__ float Asd[SC_KC][4][66];   // content rows y0-1..y0+2, x in [-1,64], zero-padded
    __shared__ float Bsd[SC_KC][6][64];   // style rows pu0..pu0+5

    int tid = threadIdx.x;
    int tp = tid & 15, tq = tid >> 4;
    int ly = tq >> 3;                      // pixel row within tile (0/1)
    int x0 = (tq & 7) * 8;                 // pixel x start
    int pu0 = p0 / PW_;

    int prow[8], pcol[8];
    #pragma unroll
    for (int v = 0; v < 8; ++v) {
        int p = p0 + tp * 8 + v; if (p > P_ - 1) p = P_ - 1;   // clamp (invalid discarded later)
        prow[v] = p / PW_ - pu0; pcol[v] = p % PW_;
    }

    float acc[8][8] = {};

    for (int c0 = 0; c0 < C_; c0 += SC_KC) {
        for (int l = tid; l < SC_KC * 4 * 66; l += 256) {
            int cc = l / 264; int rem = l - cc * 264;
            int r = rem / 66; int xw = rem - r * 66;
            int gy = y0 - 1 + r; int gx = xw - 1;
            float vv = 0.f;
            if ((unsigned)gy < 64u && (unsigned)gx < 64u)
                vv = ncb[(long)(c0 + cc) * HW_ + gy * W_ + gx];
            Asd[cc][r][xw] = vv;
        }
        for (int l = tid; l < SC_KC * 6 * 64; l += 256) {
            int cc = l / 384; int rem = l - cc * 384;
            int r = rem >> 6; int xw = rem & 63;
            int gy = pu0 + r;
            float vv = 0.f;
            if (gy < 64) vv = nsb[(long)(c0 + cc) * HW_ + gy * W_ + xw];
            Bsd[cc][r][xw] = vv;
        }
        __syncthreads();
        #pragma unroll 1                    // keep channel loop rolled (I-cache)
        for (int cc = 0; cc < SC_KC; ++cc) {
            #pragma unroll
            for (int i = 0; i < 3; ++i) {
                #pragma unroll
                for (int j = 0; j < 3; ++j) {
                    float a[8], bb[8];
                    #pragma unroll
                    for (int u = 0; u < 8; ++u) a[u] = Asd[cc][ly + i][x0 + u + j];
                    #pragma unroll
                    for (int v = 0; v < 8; ++v) bb[v] = Bsd[cc][prow[v] + i][pcol[v] + j];
                    #pragma unroll
                    for (int u = 0; u < 8; ++u)
                        #pragma unroll
                        for (int v = 0; v < 8; ++v)
                            acc[u][v] += a[u] * bb[v];
                }
            }
        }
        __syncthreads();
    }

    float rk[8]; int pg[8]; bool pvld[8];
    #pragma unroll
    for (int v = 0; v < 8; ++v) {
        int p = p0 + tp * 8 + v;
        pg[v] = p; pvld[v] = (p < P_);
        rk[v] = pvld[v] ? rkn[b * P_ + p] : 0.f;
    }
    #pragma unroll
    for (int u = 0; u < 8; ++u) {
        float best = -3.0e38f; int bp = 0x7FFFFFFF;
        #pragma unroll
        for (int v = 0; v < 8; ++v) {
            float sc = acc[u][v] * rk[v];
            bool take = pvld[v] && (sc > best || (sc == best && pg[v] < bp));
            if (take) { best = sc; bp = pg[v]; }
        }
        #pragma unroll
        for (int m = 8; m >= 1; m >>= 1) {   // reduce across tp (16 contiguous lanes)
            float ob = __shfl_xor(best, m);
            int   op = __shfl_xor(bp, m);
            if (ob > best || (ob == best && op < bp)) { best = ob; bp = op; }
        }
        if (tp == 0) {
            unsigned ub = __float_as_uint(best);
            ub = (ub & 0x80000000u) ? ~ub : (ub | 0x80000000u);   // sortable float bits
            unsigned long long enc = ((unsigned long long)ub << 32) | (unsigned)(0xFFFFFFFFu - (unsigned)bp);
            atomicMax(&packed[(long)b * HW_ + (y0 + ly) * W_ + x0 + u], enc);
        }
    }
}

// --------------------------------------------------------------------------- one-hot transpose-conv == 9-tap gather, / overlap count
__global__ __launch_bounds__(256)
void k_reasm(const unsigned long long* __restrict__ packed, const float* __restrict__ nsw,
             float* __restrict__ reasm)
{
    int b = blockIdx.x, y = blockIdx.y;
    int x = threadIdx.x, tc = threadIdx.y;          // block (64,4)
    const float* nsb = nsw + (long)b * CHW_;
    int soff[9]; float msk[9];
    #pragma unroll
    for (int dy = -1; dy <= 1; ++dy) {
        #pragma unroll
        for (int dx = -1; dx <= 1; ++dx) {
            int k = (dy + 1) * 3 + (dx + 1);
            int u = y + dy, v = x + dx;
            if ((unsigned)u < 64u && (unsigned)v < 64u) {
                unsigned long long e = packed[(long)b * HW_ + u * W_ + v];
                int p = (int)(0xFFFFFFFFu - (unsigned)(e & 0xFFFFFFFFull));
                int pu = p / PW_, pv = p - pu * PW_;
                soff[k] = (pu + (1 - dy)) * W_ + (pv + (1 - dx));   // kern[p,c,1-dy,1-dx] = ns[c, pu+1-dy, pv+1-dx]
                msk[k] = 1.f;
            } else { soff[k] = 0; msk[k] = 0.f; }
        }
    }
    int rh = (y == 0 || y == 63) ? 2 : 3;
    int rw = (x == 0 || x == 63) ? 2 : 3;
    float inv = 1.f / (float)(rh * rw);
    for (int c = tc; c < C_; c += 4) {
        const float* cb = nsb + (long)c * HW_;
        float s = 0.f;
        #pragma unroll
        for (int k = 0; k < 9; ++k) s += msk[k] * cb[soff[k]];
        reasm[((long)b * C_ + c) * HW_ + y * W_ + x] = s * inv;
    }
}

// ---------------------------------------------------------------------------
extern "C" void kernel_launch(void* const* d_in, const int* in_sizes, int n_in,
                              void* d_out, int out_size, void* d_ws, size_t ws_size,
                              hipStream_t stream)
{
    const float* content = (const float*)d_in[0];
    const float* style   = (const float*)d_in[1];
    float* out = (float*)d_out;
    float* ws  = (float*)d_ws;

    // ws layout (floats), ~176.4 MB total
    float* XC    = ws;                       // [8][C][HW] centered content(0-3)|style(4-7); later reused as reasm
    float* NC    = XC    + 8 * CHW_;         // [8][C][HW] whitened content|style
    float* SLABA = NC    + 8 * CHW_;         // [16][C][C] Y|Z ping
    float* SLABB = SLABA + 16 * CC_;         // [16][C][C] Y|Z pong (lower 8*CC doubles as cov)
    float* TBUF  = SLABB + 16 * CC_;         // [8][C][C]
    float* MEANS = TBUF  + 8 * CC_;          // [8][512]
    float* SNORM = MEANS + 4096;             // [16]
    float* Q     = SNORM + 16;               // [B][HW]
    float* RKN   = Q     + 16384;            // [B][P]
    unsigned long long* PACKED = (unsigned long long*)(RKN + 15392);  // [B][HW] u64

    float* COV   = SLABB;                    // alias: cov dead before SLABB first written (iter 2)
    float* REASM = XC;                       // alias: XC dead after whiten-apply

    hipMemsetAsync(SNORM, 0, 16 * sizeof(float), stream);
    hipMemsetAsync(PACKED, 0, (size_t)4 * HW_ * 8, stream);

    // 1. center
    k_center<<<dim3(4096), dim3(256), 0, stream>>>(content, style, XC, MEANS);

    // 2. cov = xc @ xc^T / 4095  (8 problems)
    gemm_k<GM_COV, true><<<dim3(8, 8, 8), dim3(256), 0, stream>>>(
        XC, XC, COV, nullptr, nullptr, nullptr, 512, 512, 4096, CHW_, CHW_, CC_, 0, 1.0f / 4095.0f);

    // 3. Newton-Schulz: Y->cov^{1/2}, Z->cov^{-1/2} (scaled at final iter)
    k_infnorm<<<dim3(8), dim3(256), 0, stream>>>(COV, SNORM);
    k_nsinit<<<dim3(8192), dim3(256), 0, stream>>>(COV, SNORM, TBUF, SLABA + 8 * CC_);   // T1; Z1=T1
    gemm_k<GM_SCALE_RCP, false><<<dim3(8, 8, 8), dim3(256), 0, stream>>>(                // Y1 = (cov@T1)/s
        COV, TBUF, SLABA, SNORM, nullptr, nullptr, 512, 512, 512, CC_, CC_, CC_, 0, 0.f);

    float* curS = SLABA; float* outS = SLABB;
    for (int it = 2; it <= NIT_; ++it) {
        gemm_k<GM_NST, false><<<dim3(8, 8, 8), dim3(256), 0, stream>>>(                  // T = 1.5I - 0.5*Z@Y
            curS + 8 * CC_, curS, TBUF, nullptr, nullptr, nullptr, 512, 512, 512, CC_, CC_, CC_, 0, 0.f);
        if (it == NIT_)
            gemm_k<GM_NSMUL_F, false><<<dim3(8, 8, 16), dim3(256), 0, stream>>>(         // Y2=Y@T*sqrt(s); Z2=T@Z/sqrt(s)
                curS, curS + 8 * CC_, outS, SNORM, TBUF, nullptr, 512, 512, 512, 0, 0, 0, 0, 0.f);
        else
            gemm_k<GM_NSMUL, false><<<dim3(8, 8, 16), dim3(256), 0, stream>>>(
                curS, curS + 8 * CC_, outS, SNORM, TBUF, nullptr, 512, 512, 512, 0, 0, 0, 0, 0.f);
        float* t = curS; curS = outS; outS = t;
    }
    // curS: [Y(8)|Z(8)], Y = cov^{1/2}, Z = cov^{-1/2}

    // 4. whiten apply: nc/nsw = Z @ xc   (8 problems)
    gemm_k<GM_PLAIN, false><<<dim3(8, 64, 8), dim3(256), 0, stream>>>(
        curS + 8 * CC_, XC, NC, nullptr, nullptr, nullptr, 512, 4096, 512, CC_, CHW_, CHW_, 0, 0.f);

    // 5. patch norms of whitened style
    k_q<<<dim3(4, 16), dim3(64, 4), 0, stream>>>(NC + 4 * CHW_, Q);
    k_rkn<<<dim3(4), dim3(256), 0, stream>>>(Q, RKN);

    // 6. fused score + argmax
    k_score<<<dim3(31, 32, 4), dim3(256), 0, stream>>>(NC, NC + 4 * CHW_, RKN, PACKED);

    // 7. reassembly gather
    k_reasm<<<dim3(4, 64), dim3(64, 4), 0, stream>>>(PACKED, NC + 4 * CHW_, REASM);

    // 8. recolor + blend: out = 0.5*content + 0.5*(Y_style @ reasm + smu)
    gemm_k<GM_COLOR, false><<<dim3(8, 64, 4), dim3(256), 0, stream>>>(
        curS + 4 * CC_, REASM, out, nullptr, content, MEANS + 2048,
        512, 4096, 512, CC_, CHW_, CHW_, CHW_, 0.f);
}

// Round 5
// 3656.167 us; speedup vs baseline: 3.0481x; 3.0481x over previous
//
#include <hip/hip_runtime.h>
#include <stdint.h>

// AvatarNet style-swap, MI355X. Score GEMM = split-fp16 MFMA (32x32x16),
// staging via vectorized ds_write_b128 (conflict-free).
// Pipeline: center -> cov (batched GEMM-NT) -> Newton-Schulz (cov^{+-1/2}, batched)
//        -> whiten apply -> patch-norm -> fused MFMA score + argmax (atomicMax packed u64)
//        -> one-hot transpose-conv gather -> recolor GEMM + blend epilogue.

#define C_   512
#define H_   64
#define W_   64
#define HW_  4096
#define P_   3844            // (64-2)^2 patches per image
#define PW_  62
#define NIT_ 10              // Newton-Schulz iterations

static const long CHW_ = (long)C_ * HW_;   // 2,097,152
static const long CC_  = (long)C_ * C_;    // 262,144 = 2^18

typedef _Float16 f16x8 __attribute__((ext_vector_type(8)));
typedef float    f32x16 __attribute__((ext_vector_type(16)));

enum { GM_COV = 0, GM_NST = 1, GM_PLAIN = 2, GM_SCALE_RCP = 3, GM_NSMUL = 4, GM_NSMUL_F = 5, GM_COLOR = 6 };

// ---------------------------------------------------------------------------
// Generic batched 64x64-tile fp32 GEMM, 256 threads, 4x4 micro-tile.
// ---------------------------------------------------------------------------
template<int MODE, bool TB>
__global__ __launch_bounds__(256)
void gemm_k(const float* __restrict__ A, const float* __restrict__ Bm, float* __restrict__ Cm_,
            const float* __restrict__ sarr, const float* __restrict__ ex1, const float* __restrict__ ex2,
            int M, int N, int K, long sA, long sB, long sC, long sE1, float cscale)
{
    int z = blockIdx.z;
    const float* Ab; const float* Bb; float* Cb;
    float fs = 1.0f;
    if (MODE == GM_NSMUL || MODE == GM_NSMUL_F) {
        if (z < 8) {
            Ab = A   + (long)z * CC_;          // Y
            Bb = ex1 + (long)z * CC_;          // T
            if (MODE == GM_NSMUL_F) fs = sqrtf(sarr[z]);
        } else {
            Ab = ex1 + (long)(z - 8) * CC_;    // T
            Bb = Bm  + (long)(z - 8) * CC_;    // Z
            if (MODE == GM_NSMUL_F) fs = rsqrtf(sarr[z - 8]);
        }
        Cb = Cm_ + (long)z * CC_;
    } else {
        Ab = A   + (long)z * sA;
        Bb = Bm  + (long)z * sB;
        Cb = Cm_ + (long)z * sC;
        if (MODE == GM_SCALE_RCP) fs = 1.0f / sarr[z];
    }

    __shared__ float As[16][64];
    __shared__ float Bs[16][64];

    int tid = threadIdx.x;
    int tx = tid & 15, ty = tid >> 4;
    int i0 = blockIdx.x * 64;
    int j0 = blockIdx.y * 64;

    int lr = tid >> 2;
    int lk = (tid & 3) << 2;

    float acc[4][4] = {};

    for (int k0 = 0; k0 < K; k0 += 16) {
        float4 va = *(const float4*)(Ab + (long)(i0 + lr) * K + (k0 + lk));
        As[lk + 0][lr] = va.x; As[lk + 1][lr] = va.y; As[lk + 2][lr] = va.z; As[lk + 3][lr] = va.w;
        if (TB) {
            float4 vb = *(const float4*)(Bb + (long)(j0 + lr) * K + (k0 + lk));
            Bs[lk + 0][lr] = vb.x; Bs[lk + 1][lr] = vb.y; Bs[lk + 2][lr] = vb.z; Bs[lk + 3][lr] = vb.w;
        } else {
            int kr = tid >> 4, jc = (tid & 15) << 2;
            float4 vb = *(const float4*)(Bb + (long)(k0 + kr) * N + (j0 + jc));
            *(float4*)&Bs[kr][jc] = vb;
        }
        __syncthreads();
        #pragma unroll
        for (int k = 0; k < 16; ++k) {
            float4 av = *(const float4*)&As[k][ty * 4];
            float4 bv = *(const float4*)&Bs[k][tx * 4];
            acc[0][0] += av.x * bv.x; acc[0][1] += av.x * bv.y; acc[0][2] += av.x * bv.z; acc[0][3] += av.x * bv.w;
            acc[1][0] += av.y * bv.x; acc[1][1] += av.y * bv.y; acc[1][2] += av.y * bv.z; acc[1][3] += av.y * bv.w;
            acc[2][0] += av.z * bv.x; acc[2][1] += av.z * bv.y; acc[2][2] += av.z * bv.z; acc[2][3] += av.z * bv.w;
            acc[3][0] += av.w * bv.x; acc[3][1] += av.w * bv.y; acc[3][2] += av.w * bv.z; acc[3][3] += av.w * bv.w;
        }
        __syncthreads();
    }

    #pragma unroll
    for (int u = 0; u < 4; ++u) {
        int row  = i0 + ty * 4 + u;
        int col0 = j0 + tx * 4;
        float o[4];
        if (MODE == GM_COLOR) {
            const float* cv = ex1 + (long)z * sE1 + (long)row * N + col0;
            float mu = ex2[z * C_ + row];
            #pragma unroll
            for (int v = 0; v < 4; ++v) o[v] = 0.5f * cv[v] + 0.5f * (acc[u][v] + mu);
        } else {
            #pragma unroll
            for (int v = 0; v < 4; ++v) {
                if (MODE == GM_COV)      o[v] = acc[u][v] * cscale;
                else if (MODE == GM_NST) o[v] = (row == col0 + v ? 1.5f : 0.0f) - 0.5f * acc[u][v];
                else                     o[v] = acc[u][v] * fs;
            }
        }
        *(float4*)&Cb[(long)row * N + col0] = make_float4(o[0], o[1], o[2], o[3]);
    }
}

// --------------------------------------------------------------------------- mean + center
__global__ __launch_bounds__(256)
void k_center(const float* __restrict__ content, const float* __restrict__ style,
              float* __restrict__ xc, float* __restrict__ means)
{
    int bz = blockIdx.x;
    int z = bz >> 9, c = bz & 511;
    const float* src = (z < 4) ? (content + ((long)z * C_ + c) * HW_)
                               : (style   + ((long)(z - 4) * C_ + c) * HW_);
    float* dst = xc + (long)bz * HW_;
    int tid = threadIdx.x;
    float s = 0.f;
    for (int k = tid; k < HW_; k += 256) s += src[k];
    __shared__ float red[4];
    #pragma unroll
    for (int m = 32; m >= 1; m >>= 1) s += __shfl_down(s, m);
    if ((tid & 63) == 0) red[tid >> 6] = s;
    __syncthreads();
    float mean = (red[0] + red[1] + red[2] + red[3]) * (1.0f / HW_);
    for (int k = tid; k < HW_; k += 256) dst[k] = src[k] - mean;
    if (tid == 0) means[bz] = mean;
}

// --------------------------------------------------------------------------- inf-norm of cov
__global__ void k_infnorm(const float* __restrict__ cov, float* __restrict__ snorm)
{
    int z = blockIdx.x; int tid = threadIdx.x;
    const float* Mz = cov + (long)z * CC_;
    for (int r = tid; r < C_; r += 256) {
        const float4* row = (const float4*)(Mz + (long)r * C_);
        float s = 0.f;
        for (int k = 0; k < C_ / 4; ++k) {
            float4 v = row[k];
            s += fabsf(v.x) + fabsf(v.y) + fabsf(v.z) + fabsf(v.w);
        }
        atomicMax((unsigned*)&snorm[z], __float_as_uint(s));
    }
}

// --------------------------------------------------------------------------- T1 = 1.5I - 0.5*cov/s ; Z1 = T1
__global__ void k_nsinit(const float* __restrict__ cov, const float* __restrict__ snorm,
                         float* __restrict__ T, float* __restrict__ Z1)
{
    long i = (long)blockIdx.x * 256 + threadIdx.x;
    int z = (int)(i >> 18);
    long rc = i & (CC_ - 1);
    int row = (int)(rc >> 9), col = (int)(rc & 511);
    float v = -0.5f * cov[i] / snorm[z];
    if (row == col) v += 1.5f;
    T[i] = v;
    Z1[i] = v;
}

// --------------------------------------------------------------------------- q[b,y,x] = sum_c nsw^2
__global__ void k_q(const float* __restrict__ nsw, float* __restrict__ q)
{
    int b = blockIdx.x, y = blockIdx.y * 4 + threadIdx.y, x = threadIdx.x;
    const float* base = nsw + (long)b * CHW_ + y * W_ + x;
    float s = 0.f;
    for (int c = 0; c < C_; ++c) { float v = base[(long)c * HW_]; s += v * v; }
    q[(long)b * HW_ + y * W_ + x] = s;
}

// --------------------------------------------------------------------------- rknorm[b,p] = 1/sqrt(sum 3x3 of q)
__global__ void k_rkn(const float* __restrict__ q, float* __restrict__ rkn)
{
    int b = blockIdx.x;
    const float* qb = q + (long)b * HW_;
    for (int p = threadIdx.x; p < P_; p += 256) {
        int pu = p / PW_, pv = p % PW_;
        float s = 0.f;
        #pragma unroll
        for (int i = 0; i < 3; ++i)
            #pragma unroll
            for (int j = 0; j < 3; ++j)
                s += qb[(pu + i) * W_ + pv + j];
        rkn[b * P_ + p] = rsqrtf(fmaxf(s, 1e-20f));
    }
}

// ---------------------------------------------------------------------------
// Split-fp16 MFMA score + argmax.
// Block: 256 thr (4 waves), tile = 64 pixels (one image row y0) x 256 patches.
// Wave w: 64 px x 64 patches (2 m-tiles x 2 n-tiles of 32x32x16 MFMA).
// K = 9 taps x 512 ch; chunk = 16 ch staged in LDS as hi/lo f16 planes in
// 16B channel-group cells; staging = 8 coalesced dword loads + 2 ds_write_b128
// per cell (lane-consecutive cells -> conflict-free).
// score = Ah*Bh + Ah*Bl + Al*Bh (fp32 acc); epilogue: *rkn, shfl argmax,
// atomicMax on packed u64 (sortable score | ~patch for lowest-index ties).
// ---------------------------------------------------------------------------
#define SC_CH 16
__global__ __launch_bounds__(256)
void k_score(const float* __restrict__ nc, const float* __restrict__ nsw,
             const float* __restrict__ rkn, unsigned long long* __restrict__ packed)
{
    int b  = blockIdx.z;
    int p0 = blockIdx.x * 256;
    int y0 = blockIdx.y;
    const float* ncb = nc  + (long)b * CHW_;
    const float* nsb = nsw + (long)b * CHW_;

    __shared__ __align__(16) _Float16 sA[2][2][3][66][8];  // [hi/lo][g][r][x][e]  12672 B
    __shared__ __align__(16) _Float16 sB[2][2][8][64][8];  // [hi/lo][g][r][x][e]  32768 B

    int tid  = threadIdx.x;
    int w    = tid >> 6;
    int lane = tid & 63;
    int l31  = lane & 31;
    int h    = lane >> 5;          // k-group / channel-half selector

    int pu0 = p0 / PW_;
    int pw0 = p0 + w * 64;

    int pn0 = pw0 + l31;
    int pn1 = pw0 + 32 + l31;
    int q0 = pn0 < P_ - 1 ? pn0 : P_ - 1;
    int q1 = pn1 < P_ - 1 ? pn1 : P_ - 1;
    int brow0 = q0 / PW_ - pu0, bcol0 = q0 % PW_;
    int brow1 = q1 / PW_ - pu0, bcol1 = q1 % PW_;

    f32x16 acc00 = {}, acc01 = {}, acc10 = {}, acc11 = {};

    for (int c0 = 0; c0 < C_; c0 += SC_CH) {
        // stage A: cells (g,r,x) = 2*3*66 = 396; 8 coalesced ch-loads + 2 b128 stores each
        for (int idx = tid; idx < 2 * 3 * 66; idx += 256) {
            int x = idx % 66; int gr = idx / 66;        // gr in [0,6)
            int r = gr % 3, g = gr / 3;
            int gy = y0 - 1 + r, gx = x - 1;
            bool ok = ((unsigned)gy < 64u) && ((unsigned)gx < 64u);
            const float* src = ncb + (long)(c0 + g * 8) * HW_ + gy * W_ + gx;
            f16x8 hi8, lo8;
            #pragma unroll
            for (int e = 0; e < 8; ++e) {
                float v = ok ? src[(long)e * HW_] : 0.f;
                _Float16 hi = (_Float16)v;
                hi8[e] = hi;
                lo8[e] = (_Float16)(v - (float)hi);
            }
            *(f16x8*)&sA[0][g][r][x][0] = hi8;
            *(f16x8*)&sA[1][g][r][x][0] = lo8;
        }
        // stage B: cells (g,r,x) = 2*8*64 = 1024; 4 iterations exactly
        for (int idx = tid; idx < 2 * 8 * 64; idx += 256) {
            int x = idx & 63; int gr = idx >> 6;        // gr in [0,16)
            int r = gr & 7, g = gr >> 3;
            int gy = pu0 + r;
            bool ok = gy < 64;
            const float* src = nsb + (long)(c0 + g * 8) * HW_ + gy * W_ + x;
            f16x8 hi8, lo8;
            #pragma unroll
            for (int e = 0; e < 8; ++e) {
                float v = ok ? src[(long)e * HW_] : 0.f;
                _Float16 hi = (_Float16)v;
                hi8[e] = hi;
                lo8[e] = (_Float16)(v - (float)hi);
            }
            *(f16x8*)&sB[0][g][r][x][0] = hi8;
            *(f16x8*)&sB[1][g][r][x][0] = lo8;
        }
        __syncthreads();

        #pragma unroll
        for (int i = 0; i < 3; ++i) {
            #pragma unroll
            for (int j = 0; j < 3; ++j) {
                f16x8 a0h = *(const f16x8*)&sA[0][h][i][l31 + j][0];
                f16x8 a0l = *(const f16x8*)&sA[1][h][i][l31 + j][0];
                f16x8 a1h = *(const f16x8*)&sA[0][h][i][32 + l31 + j][0];
                f16x8 a1l = *(const f16x8*)&sA[1][h][i][32 + l31 + j][0];
                f16x8 b0h = *(const f16x8*)&sB[0][h][brow0 + i][bcol0 + j][0];
                f16x8 b0l = *(const f16x8*)&sB[1][h][brow0 + i][bcol0 + j][0];
                f16x8 b1h = *(const f16x8*)&sB[0][h][brow1 + i][bcol1 + j][0];
                f16x8 b1l = *(const f16x8*)&sB[1][h][brow1 + i][bcol1 + j][0];

                acc00 = __builtin_amdgcn_mfma_f32_32x32x16_f16(a0l, b0h, acc00, 0, 0, 0);
                acc00 = __builtin_amdgcn_mfma_f32_32x32x16_f16(a0h, b0l, acc00, 0, 0, 0);
                acc00 = __builtin_amdgcn_mfma_f32_32x32x16_f16(a0h, b0h, acc00, 0, 0, 0);

                acc01 = __builtin_amdgcn_mfma_f32_32x32x16_f16(a0l, b1h, acc01, 0, 0, 0);
                acc01 = __builtin_amdgcn_mfma_f32_32x32x16_f16(a0h, b1l, acc01, 0, 0, 0);
                acc01 = __builtin_amdgcn_mfma_f32_32x32x16_f16(a0h, b1h, acc01, 0, 0, 0);

                acc10 = __builtin_amdgcn_mfma_f32_32x32x16_f16(a1l, b0h, acc10, 0, 0, 0);
                acc10 = __builtin_amdgcn_mfma_f32_32x32x16_f16(a1h, b0l, acc10, 0, 0, 0);
                acc10 = __builtin_amdgcn_mfma_f32_32x32x16_f16(a1h, b0h, acc10, 0, 0, 0);

                acc11 = __builtin_amdgcn_mfma_f32_32x32x16_f16(a1l, b1h, acc11, 0, 0, 0);
                acc11 = __builtin_amdgcn_mfma_f32_32x32x16_f16(a1h, b1l, acc11, 0, 0, 0);
                acc11 = __builtin_amdgcn_mfma_f32_32x32x16_f16(a1h, b1h, acc11, 0, 0, 0);
            }
        }
        __syncthreads();
    }

    // epilogue: scale by 1/|patch|, argmax over patches (lowest index on ties)
    bool v0 = pn0 < P_, v1 = pn1 < P_;
    float rk0 = v0 ? rkn[b * P_ + pn0] : 0.f;
    float rk1 = v1 ? rkn[b * P_ + pn1] : 0.f;

    #pragma unroll
    for (int mt = 0; mt < 2; ++mt) {
        const f32x16& A0 = mt ? acc10 : acc00;
        const f32x16& A1 = mt ? acc11 : acc01;
        #pragma unroll
        for (int r = 0; r < 16; ++r) {
            float s0 = v0 ? A0[r] * rk0 : -3.0e38f;
            float s1 = v1 ? A1[r] * rk1 : -3.0e38f;
            float best = s0; int bp = pn0;
            if (s1 > best) { best = s1; bp = pn1; }
            #pragma unroll
            for (int m = 1; m <= 16; m <<= 1) {
                float ob = __shfl_xor(best, m);
                int   op = __shfl_xor(bp, m);
                if (ob > best || (ob == best && op < bp)) { best = ob; bp = op; }
            }
            if (l31 == 0 && best > -2.9e38f) {
                int mr = (r & 3) + 8 * (r >> 2) + 4 * h;   // C/D row map (m74/m101)
                int px = mt * 32 + mr;
                unsigned ub = __float_as_uint(best);
                ub = (ub & 0x80000000u) ? ~ub : (ub | 0x80000000u);
                unsigned long long enc = ((unsigned long long)ub << 32) | (unsigned)(0xFFFFFFFFu - (unsigned)bp);
                atomicMax(&packed[(long)b * HW_ + y0 * W_ + px], enc);
            }
        }
    }
}

// --------------------------------------------------------------------------- one-hot transpose-conv == 9-tap gather, / overlap count
__global__ __launch_bounds__(256)
void k_reasm(const unsigned long long* __restrict__ packed, const float* __restrict__ nsw,
             float* __restrict__ reasm)
{
    int b = blockIdx.x, y = blockIdx.y;
    int x = threadIdx.x, tc = threadIdx.y;
    const float* nsb = nsw + (long)b * CHW_;
    int soff[9]; float msk[9];
    #pragma unroll
    for (int dy = -1; dy <= 1; ++dy) {
        #pragma unroll
        for (int dx = -1; dx <= 1; ++dx) {
            int k = (dy + 1) * 3 + (dx + 1);
            int u = y + dy, v = x + dx;
            if ((unsigned)u < 64u && (unsigned)v < 64u) {
                unsigned long long e = packed[(long)b * HW_ + u * W_ + v];
                int p = (int)(0xFFFFFFFFu - (unsigned)(e & 0xFFFFFFFFull));
                int pu = p / PW_, pv = p - pu * PW_;
                soff[k] = (pu + (1 - dy)) * W_ + (pv + (1 - dx));
                msk[k] = 1.f;
            } else { soff[k] = 0; msk[k] = 0.f; }
        }
    }
    int rh = (y == 0 || y == 63) ? 2 : 3;
    int rw = (x == 0 || x == 63) ? 2 : 3;
    float inv = 1.f / (float)(rh * rw);
    for (int c = tc; c < C_; c += 4) {
        const float* cb = nsb + (long)c * HW_;
        float s = 0.f;
        #pragma unroll
        for (int k = 0; k < 9; ++k) s += msk[k] * cb[soff[k]];
        reasm[((long)b * C_ + c) * HW_ + y * W_ + x] = s * inv;
    }
}

// ---------------------------------------------------------------------------
extern "C" void kernel_launch(void* const* d_in, const int* in_sizes, int n_in,
                              void* d_out, int out_size, void* d_ws, size_t ws_size,
                              hipStream_t stream)
{
    const float* content = (const float*)d_in[0];
    const float* style   = (const float*)d_in[1];
    float* out = (float*)d_out;
    float* ws  = (float*)d_ws;

    float* XC    = ws;                       // [8][C][HW]
    float* NC    = XC    + 8 * CHW_;         // [8][C][HW] whitened
    float* SLABA = NC    + 8 * CHW_;         // [16][C][C]
    float* SLABB = SLABA + 16 * CC_;         // [16][C][C]
    float* TBUF  = SLABB + 16 * CC_;         // [8][C][C]
    float* MEANS = TBUF  + 8 * CC_;          // [8][512]
    float* SNORM = MEANS + 4096;             // [16]
    float* Q     = SNORM + 16;               // [B][HW]
    float* RKN   = Q     + 16384;            // [B][P]
    unsigned long long* PACKED = (unsigned long long*)(RKN + 15392);  // [B][HW] u64

    float* COV   = SLABB;
    float* REASM = XC;

    hipMemsetAsync(SNORM, 0, 16 * sizeof(float), stream);
    hipMemsetAsync(PACKED, 0, (size_t)4 * HW_ * 8, stream);

    k_center<<<dim3(4096), dim3(256), 0, stream>>>(content, style, XC, MEANS);

    gemm_k<GM_COV, true><<<dim3(8, 8, 8), dim3(256), 0, stream>>>(
        XC, XC, COV, nullptr, nullptr, nullptr, 512, 512, 4096, CHW_, CHW_, CC_, 0, 1.0f / 4095.0f);

    k_infnorm<<<dim3(8), dim3(256), 0, stream>>>(COV, SNORM);
    k_nsinit<<<dim3(8192), dim3(256), 0, stream>>>(COV, SNORM, TBUF, SLABA + 8 * CC_);
    gemm_k<GM_SCALE_RCP, false><<<dim3(8, 8, 8), dim3(256), 0, stream>>>(
        COV, TBUF, SLABA, SNORM, nullptr, nullptr, 512, 512, 512, CC_, CC_, CC_, 0, 0.f);

    float* curS = SLABA; float* outS = SLABB;
    for (int it = 2; it <= NIT_; ++it) {
        gemm_k<GM_NST, false><<<dim3(8, 8, 8), dim3(256), 0, stream>>>(
            curS + 8 * CC_, curS, TBUF, nullptr, nullptr, nullptr, 512, 512, 512, CC_, CC_, CC_, 0, 0.f);
        if (it == NIT_)
            gemm_k<GM_NSMUL_F, false><<<dim3(8, 8, 16), dim3(256), 0, stream>>>(
                curS, curS + 8 * CC_, outS, SNORM, TBUF, nullptr, 512, 512, 512, 0, 0, 0, 0, 0.f);
        else
            gemm_k<GM_NSMUL, false><<<dim3(8, 8, 16), dim3(256), 0, stream>>>(
                curS, curS + 8 * CC_, outS, SNORM, TBUF, nullptr, 512, 512, 512, 0, 0, 0, 0, 0.f);
        float* t = curS; curS = outS; outS = t;
    }

    gemm_k<GM_PLAIN, false><<<dim3(8, 64, 8), dim3(256), 0, stream>>>(
        curS + 8 * CC_, XC, NC, nullptr, nullptr, nullptr, 512, 4096, 512, CC_, CHW_, CHW_, 0, 0.f);

    k_q<<<dim3(4, 16), dim3(64, 4), 0, stream>>>(NC + 4 * CHW_, Q);
    k_rkn<<<dim3(4), dim3(256), 0, stream>>>(Q, RKN);

    // fused MFMA score + argmax: grid = (p-tiles, y-rows, batch)
    k_score<<<dim3(16, 64, 4), dim3(256), 0, stream>>>(NC, NC + 4 * CHW_, RKN, PACKED);

    k_reasm<<<dim3(4, 64), dim3(64, 4), 0, stream>>>(PACKED, NC + 4 * CHW_, REASM);

    gemm_k<GM_COLOR, false><<<dim3(8, 64, 4), dim3(256), 0, stream>>>(
        curS + 4 * CC_, REASM, out, nullptr, content, MEANS + 2048,
        512, 4096, 512, CC_, CHW_, CHW_, CHW_, 0.f);
}

// Round 10
// 3009.600 us; speedup vs baseline: 3.7029x; 1.2148x over previous
//
#include <hip/hip_runtime.h>
#include <stdint.h>

// AvatarNet style-swap, MI355X. All GEMMs on MFMA (split-fp16 3-term).
// NS chain kept as hi/lo fp16 planes (symmetric matrices -> B-frag reads rows).
// Pipeline: center -> cov (MFMA) -> Newton-Schulz planes chain (MFMA)
//        -> whiten (MFMA) -> patch-norm -> fused MFMA score + argmax
//        -> one-hot transpose-conv gather -> recolor MFMA + blend epilogue.

#define C_   512
#define H_   64
#define W_   64
#define HW_  4096
#define P_   3844            // (64-2)^2 patches per image
#define PW_  62
#define NIT_ 10              // Newton-Schulz iterations

static const long CHW_ = (long)C_ * HW_;   // 2,097,152
static const long CC_  = (long)C_ * C_;    // 262,144 = 2^18

typedef _Float16 f16x8 __attribute__((ext_vector_type(8)));
typedef float    f32x16 __attribute__((ext_vector_type(16)));

#define SQ_NST  0
#define SQ_MUL  1
#define SQ_MULF 2
#define RC_COV    0
#define RC_WHITEN 1
#define RC_COLOR  2

// ---------------------------------------------------------------------------
// gemm_sq: 512x512 symmetric-chain product on hi/lo fp16 planes.
// Tile 64x64, 4 waves as 2x2 quadrants of 32x32, K-chunks of 16.
// score = Al*Bh + Ah*Bl + Ah*Bh into fp32 acc. Epilogue writes hi/lo planes.
// z<8 uses pointer set 1; z>=8 set 2 (for the Y@T / T@Z pair dispatch).
// ---------------------------------------------------------------------------
template<int MODE>
__global__ __launch_bounds__(256)
void gemm_sq(const _Float16* __restrict__ A1h, const _Float16* __restrict__ A1l,
             const _Float16* __restrict__ B1h, const _Float16* __restrict__ B1l,
             _Float16* __restrict__ D1h, _Float16* __restrict__ D1l,
             const _Float16* __restrict__ A2h, const _Float16* __restrict__ A2l,
             const _Float16* __restrict__ B2h, const _Float16* __restrict__ B2l,
             _Float16* __restrict__ D2h, _Float16* __restrict__ D2l,
             const float* __restrict__ sarr)
{
    int z = blockIdx.z; int zz = z & 7; bool sec = z >= 8;
    const _Float16* Ah = (sec ? A2h : A1h) + (long)zz * CC_;
    const _Float16* Al = (sec ? A2l : A1l) + (long)zz * CC_;
    const _Float16* Bh = (sec ? B2h : B1h) + (long)zz * CC_;
    const _Float16* Bl = (sec ? B2l : B1l) + (long)zz * CC_;
    _Float16* Dh = (sec ? D2h : D1h) + (long)zz * CC_;
    _Float16* Dl = (sec ? D2l : D1l) + (long)zz * CC_;
    float scl = 1.0f;
    if (MODE == SQ_MULF) scl = sec ? rsqrtf(sarr[zz]) : sqrtf(sarr[zz]);

    __shared__ __align__(16) _Float16 sA[2][2][64][8];   // [plane][kgrp][m][e]
    __shared__ __align__(16) _Float16 sB[2][2][64][8];

    int tid = threadIdx.x;
    int w = tid >> 6, lane = tid & 63, l31 = lane & 31, h = lane >> 5;
    int i0 = blockIdx.x * 64, j0 = blockIdx.y * 64;
    int wm = (w >> 1) * 32, wn = (w & 1) * 32;

    int spl = tid >> 7, sm = (tid >> 1) & 63, sh = tid & 1;   // staging map
    const _Float16* Asrc = spl ? Al : Ah;
    const _Float16* Bsrc = spl ? Bl : Bh;

    f32x16 acc = {};
    for (int c0 = 0; c0 < 512; c0 += 16) {
        *(f16x8*)&sA[spl][sh][sm][0] = *(const f16x8*)(Asrc + (long)(i0 + sm) * 512 + c0 + sh * 8);
        // symmetry: B-frag (col n, k contig) = row n of row-major B
        *(f16x8*)&sB[spl][sh][sm][0] = *(const f16x8*)(Bsrc + (long)(j0 + sm) * 512 + c0 + sh * 8);
        __syncthreads();
        f16x8 ah = *(const f16x8*)&sA[0][h][wm + l31][0];
        f16x8 al = *(const f16x8*)&sA[1][h][wm + l31][0];
        f16x8 bh = *(const f16x8*)&sB[0][h][wn + l31][0];
        f16x8 bl = *(const f16x8*)&sB[1][h][wn + l31][0];
        acc = __builtin_amdgcn_mfma_f32_32x32x16_f16(al, bh, acc, 0, 0, 0);
        acc = __builtin_amdgcn_mfma_f32_32x32x16_f16(ah, bl, acc, 0, 0, 0);
        acc = __builtin_amdgcn_mfma_f32_32x32x16_f16(ah, bh, acc, 0, 0, 0);
        __syncthreads();
    }
    #pragma unroll
    for (int r = 0; r < 16; ++r) {
        int row = i0 + wm + (r & 3) + 8 * (r >> 2) + 4 * h;   // C/D map (m74/m101)
        int col = j0 + wn + l31;
        float v = acc[r];
        if (MODE == SQ_NST) v = (row == col ? 1.5f : 0.0f) - 0.5f * v;
        else                v *= scl;
        _Float16 hi = (_Float16)v;
        Dh[(long)row * 512 + col] = hi;
        Dl[(long)row * 512 + col] = (_Float16)(v - (float)hi);
    }
}

// ---------------------------------------------------------------------------
// gemm_rect: M=512 x N(512|4096), MFMA split-fp16.
// Tile 64(m) x 128(n), 4 waves (2m x 2n), each wave 32m x 64n (2 accs).
// COV:    A=xc fp32(cvt), B=xc rows (TB), K=4096, D=cov*1/4095 (fp32)
// WHITEN: A=Z planes,     B=xc [k][n] fp32(cvt), K=512, D=nc (fp32)
// COLOR:  A=Y planes(z+4),B=reasm [k][n] fp32(cvt), K=512, D=blend out
// ---------------------------------------------------------------------------
template<int MODE>
__global__ __launch_bounds__(256)
void gemm_rect(const _Float16* __restrict__ APh, const _Float16* __restrict__ APl,
               const float* __restrict__ Asrc32, const float* __restrict__ Bsrc32,
               float* __restrict__ Dout, const float* __restrict__ content,
               const float* __restrict__ means)
{
    const int K = (MODE == RC_COV) ? 4096 : 512;
    int z = blockIdx.z;
    int tid = threadIdx.x;
    int w = tid >> 6, lane = tid & 63, l31 = lane & 31, h = lane >> 5;
    int i0 = blockIdx.x * 64, j0 = blockIdx.y * 128;
    int wm = (w >> 1) * 32, wn = (w & 1) * 64;

    __shared__ __align__(16) _Float16 sA[2][2][64][8];
    __shared__ __align__(16) _Float16 sB[2][2][128][8];

    const float* Bz = Bsrc32 + (long)z * CHW_;
    int az = (MODE == RC_COLOR) ? z + 4 : z;

    f32x16 acc0 = {}, acc1 = {};

    for (int c0 = 0; c0 < K; c0 += 16) {
        // ---- stage A
        if (MODE == RC_COV) {
            int m = tid >> 2, kq = tid & 3;
            const float* a = Asrc32 + (long)z * CHW_ + (long)(i0 + m) * HW_ + c0 + kq * 4;
            float4 va = *(const float4*)a;
            _Float16 hi[4], lo[4];
            float vv[4] = {va.x, va.y, va.z, va.w};
            #pragma unroll
            for (int e = 0; e < 4; ++e) { hi[e] = (_Float16)vv[e]; lo[e] = (_Float16)(vv[e] - (float)hi[e]); }
            *(__attribute__((ext_vector_type(4))) _Float16*)&sA[0][kq >> 1][m][(kq & 1) * 4] =
                *(__attribute__((ext_vector_type(4))) _Float16*)hi;
            *(__attribute__((ext_vector_type(4))) _Float16*)&sA[1][kq >> 1][m][(kq & 1) * 4] =
                *(__attribute__((ext_vector_type(4))) _Float16*)lo;
        } else {
            int spl = tid >> 7, sm = (tid >> 1) & 63, sh = tid & 1;
            const _Float16* a = (spl ? APl : APh) + (long)az * CC_ + (long)(i0 + sm) * 512 + c0 + sh * 8;
            *(f16x8*)&sA[spl][sh][sm][0] = *(const f16x8*)a;
        }
        // ---- stage B
        if (MODE == RC_COV) {
            // B[n][k] = xc row (j0+n), k=pos contig
            int n = tid >> 1, sh = tid & 1;
            const float* b = Bz + (long)(j0 + n) * HW_ + c0 + sh * 8;
            float4 v0 = *(const float4*)b, v1 = *(const float4*)(b + 4);
            float vv[8] = {v0.x, v0.y, v0.z, v0.w, v1.x, v1.y, v1.z, v1.w};
            f16x8 hi8, lo8;
            #pragma unroll
            for (int e = 0; e < 8; ++e) { _Float16 hh = (_Float16)vv[e]; hi8[e] = hh; lo8[e] = (_Float16)(vv[e] - (float)hh); }
            *(f16x8*)&sB[0][sh][n][0] = hi8;
            *(f16x8*)&sB[1][sh][n][0] = lo8;
        } else {
            // B[k][n]: per-col k-gather (coalesced across lanes in n)
            int n = tid & 127, sh = tid >> 7;
            const float* b = Bz + (long)(c0 + sh * 8) * HW_ + j0 + n;
            f16x8 hi8, lo8;
            #pragma unroll
            for (int e = 0; e < 8; ++e) {
                float v = b[(long)e * HW_];
                _Float16 hh = (_Float16)v; hi8[e] = hh; lo8[e] = (_Float16)(v - (float)hh);
            }
            *(f16x8*)&sB[0][sh][n][0] = hi8;
            *(f16x8*)&sB[1][sh][n][0] = lo8;
        }
        __syncthreads();
        f16x8 ah = *(const f16x8*)&sA[0][h][wm + l31][0];
        f16x8 al = *(const f16x8*)&sA[1][h][wm + l31][0];
        f16x8 b0h = *(const f16x8*)&sB[0][h][wn + l31][0];
        f16x8 b0l = *(const f16x8*)&sB[1][h][wn + l31][0];
        f16x8 b1h = *(const f16x8*)&sB[0][h][wn + 32 + l31][0];
        f16x8 b1l = *(const f16x8*)&sB[1][h][wn + 32 + l31][0];
        acc0 = __builtin_amdgcn_mfma_f32_32x32x16_f16(al, b0h, acc0, 0, 0, 0);
        acc0 = __builtin_amdgcn_mfma_f32_32x32x16_f16(ah, b0l, acc0, 0, 0, 0);
        acc0 = __builtin_amdgcn_mfma_f32_32x32x16_f16(ah, b0h, acc0, 0, 0, 0);
        acc1 = __builtin_amdgcn_mfma_f32_32x32x16_f16(al, b1h, acc1, 0, 0, 0);
        acc1 = __builtin_amdgcn_mfma_f32_32x32x16_f16(ah, b1l, acc1, 0, 0, 0);
        acc1 = __builtin_amdgcn_mfma_f32_32x32x16_f16(ah, b1h, acc1, 0, 0, 0);
        __syncthreads();
    }

    #pragma unroll
    for (int nt = 0; nt < 2; ++nt) {
        const f32x16& A = nt ? acc1 : acc0;
        #pragma unroll
        for (int r = 0; r < 16; ++r) {
            int row = i0 + wm + (r & 3) + 8 * (r >> 2) + 4 * h;
            int col = j0 + wn + nt * 32 + l31;
            if (MODE == RC_COV) {
                Dout[(long)z * CC_ + (long)row * 512 + col] = A[r] * (1.0f / 4095.0f);
            } else if (MODE == RC_WHITEN) {
                Dout[(long)z * CHW_ + (long)row * HW_ + col] = A[r];
            } else {
                long idx = (long)z * CHW_ + (long)row * HW_ + col;
                float mu = means[(z + 4) * C_ + row];
                Dout[idx] = 0.5f * content[idx] + 0.5f * (A[r] + mu);
            }
        }
    }
}

// --------------------------------------------------------------------------- mean + center
__global__ __launch_bounds__(256)
void k_center(const float* __restrict__ content, const float* __restrict__ style,
              float* __restrict__ xc, float* __restrict__ means)
{
    int bz = blockIdx.x;
    int z = bz >> 9, c = bz & 511;
    const float* src = (z < 4) ? (content + ((long)z * C_ + c) * HW_)
                               : (style   + ((long)(z - 4) * C_ + c) * HW_);
    float* dst = xc + (long)bz * HW_;
    int tid = threadIdx.x;
    float s = 0.f;
    for (int k = tid; k < HW_; k += 256) s += src[k];
    __shared__ float red[4];
    #pragma unroll
    for (int m = 32; m >= 1; m >>= 1) s += __shfl_down(s, m);
    if ((tid & 63) == 0) red[tid >> 6] = s;
    __syncthreads();
    float mean = (red[0] + red[1] + red[2] + red[3]) * (1.0f / HW_);
    for (int k = tid; k < HW_; k += 256) dst[k] = src[k] - mean;
    if (tid == 0) means[bz] = mean;
}

// --------------------------------------------------------------------------- inf-norm of cov
__global__ void k_infnorm(const float* __restrict__ cov, float* __restrict__ snorm)
{
    int z = blockIdx.x; int tid = threadIdx.x;
    const float* Mz = cov + (long)z * CC_;
    for (int r = tid; r < C_; r += 256) {
        const float4* row = (const float4*)(Mz + (long)r * C_);
        float s = 0.f;
        for (int k = 0; k < C_ / 4; ++k) {
            float4 v = row[k];
            s += fabsf(v.x) + fabsf(v.y) + fabsf(v.z) + fabsf(v.w);
        }
        atomicMax((unsigned*)&snorm[z], __float_as_uint(s));
    }
}

// --------------------------------------------------------------------------- covs = cov/s ; T1 = 1.5I-0.5covs ; Z1 = T1  (all hi/lo planes)
__global__ void k_nsinit(const float* __restrict__ cov, const float* __restrict__ snorm,
                         _Float16* __restrict__ CVH, _Float16* __restrict__ CVL,
                         _Float16* __restrict__ TH,  _Float16* __restrict__ TL,
                         _Float16* __restrict__ ZH,  _Float16* __restrict__ ZL)
{
    long i = (long)blockIdx.x * 256 + threadIdx.x;     // 8*CC
    int z = (int)(i >> 18);
    long rc = i & (CC_ - 1);
    int row = (int)(rc >> 9), col = (int)(rc & 511);
    float cs = cov[i] / snorm[z];
    float t = (row == col ? 1.5f : 0.0f) - 0.5f * cs;
    _Float16 ch = (_Float16)cs; CVH[i] = ch; CVL[i] = (_Float16)(cs - (float)ch);
    _Float16 th = (_Float16)t;  TH[i] = th;  TL[i] = (_Float16)(t - (float)th);
    ZH[i] = th; ZL[i] = TL[i];
}

// --------------------------------------------------------------------------- q[b,y,x] = sum_c nsw^2
__global__ void k_q(const float* __restrict__ nsw, float* __restrict__ q)
{
    int b = blockIdx.x, y = blockIdx.y * 4 + threadIdx.y, x = threadIdx.x;
    const float* base = nsw + (long)b * CHW_ + y * W_ + x;
    float s = 0.f;
    for (int c = 0; c < C_; ++c) { float v = base[(long)c * HW_]; s += v * v; }
    q[(long)b * HW_ + y * W_ + x] = s;
}

// --------------------------------------------------------------------------- rknorm[b,p] = 1/sqrt(sum 3x3 of q)
__global__ void k_rkn(const float* __restrict__ q, float* __restrict__ rkn)
{
    int b = blockIdx.x;
    const float* qb = q + (long)b * HW_;
    for (int p = threadIdx.x; p < P_; p += 256) {
        int pu = p / PW_, pv = p % PW_;
        float s = 0.f;
        #pragma unroll
        for (int i = 0; i < 3; ++i)
            #pragma unroll
            for (int j = 0; j < 3; ++j)
                s += qb[(pu + i) * W_ + pv + j];
        rkn[b * P_ + p] = rsqrtf(fmaxf(s, 1e-20f));
    }
}

// ---------------------------------------------------------------------------
// Split-fp16 MFMA score + argmax (measured R5: 1730us, MfmaUtil 51%).
// ---------------------------------------------------------------------------
#define SC_CH 16
__global__ __launch_bounds__(256)
void k_score(const float* __restrict__ nc, const float* __restrict__ nsw,
             const float* __restrict__ rkn, unsigned long long* __restrict__ packed)
{
    int b  = blockIdx.z;
    int p0 = blockIdx.x * 256;
    int y0 = blockIdx.y;
    const float* ncb = nc  + (long)b * CHW_;
    const float* nsb = nsw + (long)b * CHW_;

    __shared__ __align__(16) _Float16 sA[2][2][3][66][8];
    __shared__ __align__(16) _Float16 sB[2][2][8][64][8];

    int tid  = threadIdx.x;
    int w    = tid >> 6;
    int lane = tid & 63;
    int l31  = lane & 31;
    int h    = lane >> 5;

    int pu0 = p0 / PW_;
    int pw0 = p0 + w * 64;

    int pn0 = pw0 + l31;
    int pn1 = pw0 + 32 + l31;
    int q0 = pn0 < P_ - 1 ? pn0 : P_ - 1;
    int q1 = pn1 < P_ - 1 ? pn1 : P_ - 1;
    int brow0 = q0 / PW_ - pu0, bcol0 = q0 % PW_;
    int brow1 = q1 / PW_ - pu0, bcol1 = q1 % PW_;

    f32x16 acc00 = {}, acc01 = {}, acc10 = {}, acc11 = {};

    for (int c0 = 0; c0 < C_; c0 += SC_CH) {
        for (int idx = tid; idx < 2 * 3 * 66; idx += 256) {
            int x = idx % 66; int gr = idx / 66;
            int r = gr % 3, g = gr / 3;
            int gy = y0 - 1 + r, gx = x - 1;
            bool ok = ((unsigned)gy < 64u) && ((unsigned)gx < 64u);
            const float* src = ncb + (long)(c0 + g * 8) * HW_ + gy * W_ + gx;
            f16x8 hi8, lo8;
            #pragma unroll
            for (int e = 0; e < 8; ++e) {
                float v = ok ? src[(long)e * HW_] : 0.f;
                _Float16 hi = (_Float16)v;
                hi8[e] = hi;
                lo8[e] = (_Float16)(v - (float)hi);
            }
            *(f16x8*)&sA[0][g][r][x][0] = hi8;
            *(f16x8*)&sA[1][g][r][x][0] = lo8;
        }
        for (int idx = tid; idx < 2 * 8 * 64; idx += 256) {
            int x = idx & 63; int gr = idx >> 6;
            int r = gr & 7, g = gr >> 3;
            int gy = pu0 + r;
            bool ok = gy < 64;
            const float* src = nsb + (long)(c0 + g * 8) * HW_ + gy * W_ + x;
            f16x8 hi8, lo8;
            #pragma unroll
            for (int e = 0; e < 8; ++e) {
                float v = ok ? src[(long)e * HW_] : 0.f;
                _Float16 hi = (_Float16)v;
                hi8[e] = hi;
                lo8[e] = (_Float16)(v - (float)hi);
            }
            *(f16x8*)&sB[0][g][r][x][0] = hi8;
            *(f16x8*)&sB[1][g][r][x][0] = lo8;
        }
        __syncthreads();

        #pragma unroll
        for (int i = 0; i < 3; ++i) {
            #pragma unroll
            for (int j = 0; j < 3; ++j) {
                f16x8 a0h = *(const f16x8*)&sA[0][h][i][l31 + j][0];
                f16x8 a0l = *(const f16x8*)&sA[1][h][i][l31 + j][0];
                f16x8 a1h = *(const f16x8*)&sA[0][h][i][32 + l31 + j][0];
                f16x8 a1l = *(const f16x8*)&sA[1][h][i][32 + l31 + j][0];
                f16x8 b0h = *(const f16x8*)&sB[0][h][brow0 + i][bcol0 + j][0];
                f16x8 b0l = *(const f16x8*)&sB[1][h][brow0 + i][bcol0 + j][0];
                f16x8 b1h = *(const f16x8*)&sB[0][h][brow1 + i][bcol1 + j][0];
                f16x8 b1l = *(const f16x8*)&sB[1][h][brow1 + i][bcol1 + j][0];

                acc00 = __builtin_amdgcn_mfma_f32_32x32x16_f16(a0l, b0h, acc00, 0, 0, 0);
                acc00 = __builtin_amdgcn_mfma_f32_32x32x16_f16(a0h, b0l, acc00, 0, 0, 0);
                acc00 = __builtin_amdgcn_mfma_f32_32x32x16_f16(a0h, b0h, acc00, 0, 0, 0);

                acc01 = __builtin_amdgcn_mfma_f32_32x32x16_f16(a0l, b1h, acc01, 0, 0, 0);
                acc01 = __builtin_amdgcn_mfma_f32_32x32x16_f16(a0h, b1l, acc01, 0, 0, 0);
                acc01 = __builtin_amdgcn_mfma_f32_32x32x16_f16(a0h, b1h, acc01, 0, 0, 0);

                acc10 = __builtin_amdgcn_mfma_f32_32x32x16_f16(a1l, b0h, acc10, 0, 0, 0);
                acc10 = __builtin_amdgcn_mfma_f32_32x32x16_f16(a1h, b0l, acc10, 0, 0, 0);
                acc10 = __builtin_amdgcn_mfma_f32_32x32x16_f16(a1h, b0h, acc10, 0, 0, 0);

                acc11 = __builtin_amdgcn_mfma_f32_32x32x16_f16(a1l, b1h, acc11, 0, 0, 0);
                acc11 = __builtin_amdgcn_mfma_f32_32x32x16_f16(a1h, b1l, acc11, 0, 0, 0);
                acc11 = __builtin_amdgcn_mfma_f32_32x32x16_f16(a1h, b1h, acc11, 0, 0, 0);
            }
        }
        __syncthreads();
    }

    bool v0 = pn0 < P_, v1 = pn1 < P_;
    float rk0 = v0 ? rkn[b * P_ + pn0] : 0.f;
    float rk1 = v1 ? rkn[b * P_ + pn1] : 0.f;

    #pragma unroll
    for (int mt = 0; mt < 2; ++mt) {
        const f32x16& A0 = mt ? acc10 : acc00;
        const f32x16& A1 = mt ? acc11 : acc01;
        #pragma unroll
        for (int r = 0; r < 16; ++r) {
            float s0 = v0 ? A0[r] * rk0 : -3.0e38f;
            float s1 = v1 ? A1[r] * rk1 : -3.0e38f;
            float best = s0; int bp = pn0;
            if (s1 > best) { best = s1; bp = pn1; }
            #pragma unroll
            for (int m = 1; m <= 16; m <<= 1) {
                float ob = __shfl_xor(best, m);
                int   op = __shfl_xor(bp, m);
                if (ob > best || (ob == best && op < bp)) { best = ob; bp = op; }
            }
            if (l31 == 0 && best > -2.9e38f) {
                int mr = (r & 3) + 8 * (r >> 2) + 4 * h;
                int px = mt * 32 + mr;
                unsigned ub = __float_as_uint(best);
                ub = (ub & 0x80000000u) ? ~ub : (ub | 0x80000000u);
                unsigned long long enc = ((unsigned long long)ub << 32) | (unsigned)(0xFFFFFFFFu - (unsigned)bp);
                atomicMax(&packed[(long)b * HW_ + y0 * W_ + px], enc);
            }
        }
    }
}

// --------------------------------------------------------------------------- one-hot transpose-conv == 9-tap gather, / overlap count
__global__ __launch_bounds__(256)
void k_reasm(const unsigned long long* __restrict__ packed, const float* __restrict__ nsw,
             float* __restrict__ reasm)
{
    int b = blockIdx.x, y = blockIdx.y;
    int x = threadIdx.x, tc = threadIdx.y;
    const float* nsb = nsw + (long)b * CHW_;
    int soff[9]; float msk[9];
    #pragma unroll
    for (int dy = -1; dy <= 1; ++dy) {
        #pragma unroll
        for (int dx = -1; dx <= 1; ++dx) {
            int k = (dy + 1) * 3 + (dx + 1);
            int u = y + dy, v = x + dx;
            if ((unsigned)u < 64u && (unsigned)v < 64u) {
                unsigned long long e = packed[(long)b * HW_ + u * W_ + v];
                int p = (int)(0xFFFFFFFFu - (unsigned)(e & 0xFFFFFFFFull));
                int pu = p / PW_, pv = p - pu * PW_;
                soff[k] = (pu + (1 - dy)) * W_ + (pv + (1 - dx));
                msk[k] = 1.f;
            } else { soff[k] = 0; msk[k] = 0.f; }
        }
    }
    int rh = (y == 0 || y == 63) ? 2 : 3;
    int rw = (x == 0 || x == 63) ? 2 : 3;
    float inv = 1.f / (float)(rh * rw);
    for (int c = tc; c < C_; c += 4) {
        const float* cb = nsb + (long)c * HW_;
        float s = 0.f;
        #pragma unroll
        for (int k = 0; k < 9; ++k) s += msk[k] * cb[soff[k]];
        reasm[((long)b * C_ + c) * HW_ + y * W_ + x] = s * inv;
    }
}

// ---------------------------------------------------------------------------
extern "C" void kernel_launch(void* const* d_in, const int* in_sizes, int n_in,
                              void* d_out, int out_size, void* d_ws, size_t ws_size,
                              hipStream_t stream)
{
    const float* content = (const float*)d_in[0];
    const float* style   = (const float*)d_in[1];
    float* out = (float*)d_out;

    // ---- ws layout (~160.3 MB)
    char* base = (char*)d_ws;
    float* XC = (float*)base;                         // [8][C][HW] fp32, 64MB
    float* NC = XC + 8 * CHW_;                        // [8][C][HW] fp32, 64MB (whiten out)
    // pre-whiten aliases inside NC region (all dead before whiten writes NC):
    char* ncb = (char*)NC;
    float*    COV = (float*)ncb;                      //  8MB fp32 cov
    _Float16* CVH = (_Float16*)(ncb + (8 << 20));     //  4MB covs hi
    _Float16* CVL = (_Float16*)(ncb + (12 << 20));    //  4MB covs lo
    _Float16* TH  = (_Float16*)(ncb + (16 << 20));    //  4MB T hi
    _Float16* TL  = (_Float16*)(ncb + (20 << 20));    //  4MB T lo
    // Y/Z plane ping-pong (live through color): 32MB
    char* q = (char*)(NC + 8 * CHW_);
    _Float16* YaH = (_Float16*)q;             _Float16* YaL = (_Float16*)(q + (4 << 20));
    _Float16* ZaH = (_Float16*)(q + (8 << 20));  _Float16* ZaL = (_Float16*)(q + (12 << 20));
    _Float16* YbH = (_Float16*)(q + (16 << 20)); _Float16* YbL = (_Float16*)(q + (20 << 20));
    _Float16* ZbH = (_Float16*)(q + (24 << 20)); _Float16* ZbL = (_Float16*)(q + (28 << 20));
    char* t = q + (32 << 20);
    float* MEANS = (float*)t;                         t += 4096 * 4;
    float* SNORM = (float*)t;                         t += 16 * 4;
    float* Q     = (float*)t;                         t += 16384 * 4;
    float* RKN   = (float*)t;                         t += 15392 * 4;
    unsigned long long* PACKED = (unsigned long long*)t;   // [B][HW] u64, 128KB

    float* REASM = XC;   // XC dead after whiten

    hipMemsetAsync(SNORM, 0, 16 * sizeof(float), stream);
    hipMemsetAsync(PACKED, 0, (size_t)4 * HW_ * 8, stream);

    // 1. center
    k_center<<<dim3(4096), dim3(256), 0, stream>>>(content, style, XC, MEANS);

    // 2. cov = xc@xc^T / 4095 (MFMA)
    gemm_rect<RC_COV><<<dim3(8, 4, 8), dim3(256), 0, stream>>>(
        nullptr, nullptr, XC, XC, COV, nullptr, nullptr);

    // 3. Newton-Schulz on hi/lo planes
    k_infnorm<<<dim3(8), dim3(256), 0, stream>>>(COV, SNORM);
    k_nsinit<<<dim3(8192), dim3(256), 0, stream>>>(COV, SNORM, CVH, CVL, TH, TL, ZaH, ZaL);
    // Y1 = covs @ T1  -> Ya
    gemm_sq<SQ_MUL><<<dim3(8, 8, 8), dim3(256), 0, stream>>>(
        CVH, CVL, TH, TL, YaH, YaL, CVH, CVL, TH, TL, YaH, YaL, nullptr);

    _Float16 *YcH = YaH, *YcL = YaL, *ZcH = ZaH, *ZcL = ZaL;
    _Float16 *YnH = YbH, *YnL = YbL, *ZnH = ZbH, *ZnL = ZbL;
    for (int it = 2; it <= NIT_; ++it) {
        gemm_sq<SQ_NST><<<dim3(8, 8, 8), dim3(256), 0, stream>>>(        // T = 1.5I - 0.5 Z@Y
            ZcH, ZcL, YcH, YcL, TH, TL, ZcH, ZcL, YcH, YcL, TH, TL, nullptr);
        if (it == NIT_)
            gemm_sq<SQ_MULF><<<dim3(8, 8, 16), dim3(256), 0, stream>>>(  // Y@T*sqrt(s); T@Z/sqrt(s)
                YcH, YcL, TH, TL, YnH, YnL, TH, TL, ZcH, ZcL, ZnH, ZnL, SNORM);
        else
            gemm_sq<SQ_MUL><<<dim3(8, 8, 16), dim3(256), 0, stream>>>(
                YcH, YcL, TH, TL, YnH, YnL, TH, TL, ZcH, ZcL, ZnH, ZnL, nullptr);
        _Float16* s;
        s = YcH; YcH = YnH; YnH = s;  s = YcL; YcL = YnL; YnL = s;
        s = ZcH; ZcH = ZnH; ZnH = s;  s = ZcL; ZcL = ZnL; ZnL = s;
    }
    // Yc/Zc = cov^{1/2}, cov^{-1/2} planes

    // 4. whiten: nc = Z @ xc (MFMA)
    gemm_rect<RC_WHITEN><<<dim3(8, 32, 8), dim3(256), 0, stream>>>(
        ZcH, ZcL, nullptr, XC, NC, nullptr, nullptr);

    // 5. patch norms
    k_q<<<dim3(4, 16), dim3(64, 4), 0, stream>>>(NC + 4 * CHW_, Q);
    k_rkn<<<dim3(4), dim3(256), 0, stream>>>(Q, RKN);

    // 6. fused MFMA score + argmax
    k_score<<<dim3(16, 64, 4), dim3(256), 0, stream>>>(NC, NC + 4 * CHW_, RKN, PACKED);

    // 7. reassembly gather
    k_reasm<<<dim3(4, 64), dim3(64, 4), 0, stream>>>(PACKED, NC + 4 * CHW_, REASM);

    // 8. recolor + blend: out = 0.5*content + 0.5*(Y_style @ reasm + smu) (MFMA)
    gemm_rect<RC_COLOR><<<dim3(8, 32, 4), dim3(256), 0, stream>>>(
        YcH, YcL, nullptr, REASM, out, content, MEANS);
}